// Round 1
// baseline (972.235 us; speedup 1.0000x reference)
//
#include <hip/hip_runtime.h>

#define DEVINL __device__ __forceinline__

constexpr int B_ = 8, N_ = 1024, D_ = 64, H_ = 4, QV_ = 32;
constexpr int C_ = 129, K_ = 16, M_ = 4096;
constexpr int CP = 132;              // padded C (multiple of 4)
constexpr int NG = B_ * N_;          // 8192 nodes total

// ---- workspace layout (float offsets) ----
constexpr size_t o_Wvp   = 0;                                   // H*C*CP padded Wv
constexpr size_t o_q     = o_Wvp + (size_t)H_ * C_ * CP;        // H*NG*K
constexpr size_t o_k     = o_q   + (size_t)H_ * NG * K_;        // H*NG*K
constexpr size_t o_v     = o_k   + (size_t)H_ * NG * K_;        // H*NG*CP (padded)
constexpr size_t o_hp    = o_v   + (size_t)H_ * NG * CP;        // M*516 attn_cat
constexpr size_t o_cpost = o_hp  + (size_t)M_ * 516;            // M*CP
// aliases (lifetimes disjoint)
constexpr size_t o_pru = o_v;      // 8*M*64  (after attn, v dead)
constexpr size_t o_cin = o_q;      // M*CP    (after attn, q+k dead)
constexpr size_t o_pc  = o_hp;     // 8*M*64  (after mlp, hp dead)

DEVINL float4 ld4(const float* p) { return *reinterpret_cast<const float4*>(p); }
DEVINL void st4(float* p, float4 v) { *reinterpret_cast<float4*>(p) = v; }

// ---------------- K0: pad Wv [H][C][C] -> [H][C][CP] (zero pad cols) ----------------
__global__ void k_prep(const float* __restrict__ Wv, float* __restrict__ Wvp) {
    int idx = blockIdx.x * 256 + threadIdx.x;
    const int tot = H_ * C_ * CP;
    if (idx >= tot) return;
    int hh = idx / (C_ * CP); int rem = idx - hh * C_ * CP;
    int cc = rem / CP;        int o  = rem - cc * CP;
    Wvp[idx] = (o < C_) ? Wv[(hh * C_ + cc) * C_ + o] : 0.f;
}

// ---------------- K1: combined -> q,k (all nodes), v (padded) ----------------
__global__ __launch_bounds__(256) void k_qkv(
    const float* __restrict__ x, const float* __restrict__ h,
    const float* __restrict__ Wq, const float* __restrict__ bq,
    const float* __restrict__ Wk, const float* __restrict__ bk,
    const float* __restrict__ Wvp, const float* __restrict__ bv,
    float* __restrict__ qo, float* __restrict__ ko, float* __restrict__ vo) {
    __shared__ float Cs[64][CP];
    const int t = threadIdx.x;
    const int g0 = blockIdx.x * 64;
    const int hh = blockIdx.y;
    for (int idx = t; idx < 64 * C_; idx += 256) {
        int r = idx / C_, cc = idx - r * C_;
        int g = g0 + r; int b = g >> 10, n = g & (N_ - 1);
        Cs[r][cc] = (cc < 65) ? x[(b * N_ + n) * 65 + cc]
                              : h[(b * N_ + n) * D_ + (cc - 65)];
    }
    __syncthreads();
    // q and k: thread -> row r=t>>2, k-quad kb=(t&3)*4
    {
        const int r = t >> 2, kb = (t & 3) * 4;
        float aq[4], ak[4];
#pragma unroll
        for (int j = 0; j < 4; ++j) { aq[j] = bq[hh * K_ + kb + j]; ak[j] = bk[hh * K_ + kb + j]; }
        for (int cc = 0; cc < C_; ++cc) {
            float s = Cs[r][cc];
            float4 wq = ld4(&Wq[(size_t)(hh * C_ + cc) * K_ + kb]);
            float4 wk = ld4(&Wk[(size_t)(hh * C_ + cc) * K_ + kb]);
            aq[0] += s * wq.x; aq[1] += s * wq.y; aq[2] += s * wq.z; aq[3] += s * wq.w;
            ak[0] += s * wk.x; ak[1] += s * wk.y; ak[2] += s * wk.z; ak[3] += s * wk.w;
        }
        size_t gi = (size_t)(hh * NG + g0 + r) * K_ + kb;
        st4(&qo[gi], make_float4(aq[0], aq[1], aq[2], aq[3]));
        st4(&ko[gi], make_float4(ak[0], ak[1], ak[2], ak[3]));
    }
    // v main cols 0..127 (float4 per thread-output)
    for (int jj = 0; jj < 8; ++jj) {
        int idx = t + 256 * jj;
        int r = idx >> 5, o4 = (idx & 31) * 4;
        float a0 = bv[hh * C_ + o4 + 0], a1 = bv[hh * C_ + o4 + 1],
              a2 = bv[hh * C_ + o4 + 2], a3 = bv[hh * C_ + o4 + 3];
        for (int cc = 0; cc < C_; ++cc) {
            float s = Cs[r][cc];
            float4 w = ld4(&Wvp[(size_t)(hh * C_ + cc) * CP + o4]);
            a0 += s * w.x; a1 += s * w.y; a2 += s * w.z; a3 += s * w.w;
        }
        st4(&vo[(size_t)(hh * NG + g0 + r) * CP + o4], make_float4(a0, a1, a2, a3));
    }
    // v col 128 + zero pads
    if (t < 64) {
        int r = t;
        float a = bv[hh * C_ + 128];
        for (int cc = 0; cc < C_; ++cc) a += Cs[r][cc] * Wvp[(size_t)(hh * C_ + cc) * CP + 128];
        float* vp = &vo[(size_t)(hh * NG + g0 + r) * CP];
        vp[128] = a; vp[129] = 0.f; vp[130] = 0.f; vp[131] = 0.f;
    }
}

// ---------------- K3: fused masked-leaky-softmax attention, selected rows ----------------
// block: (row-tile of 32 selected rows, head). 16 col-tiles of 64.
__global__ __launch_bounds__(256) void k_attn(
    const float* __restrict__ qg, const float* __restrict__ kg, const float* __restrict__ vg,
    const int* __restrict__ adj, const int* __restrict__ nodes_b, const int* __restrict__ nodes_n,
    float* __restrict__ hp) {
    __shared__ float Ks[64][20];
    __shared__ float Vs[64][CP];
    __shared__ float Pt[64][36];
    __shared__ float Linv[32];
    __shared__ int Nrow[32];
    const int t = threadIdx.x;
    const int m0 = blockIdx.x * 32;
    const int hh = blockIdx.y;
    const int b = nodes_b[m0];
    if (t < 32) Nrow[t] = nodes_n[m0 + t];
    __syncthreads();
    const int sr = t >> 3, sc0 = t & 7;              // score mapping
    float qreg[16];
    {
        const float* qp = &qg[(size_t)(hh * NG + b * N_ + Nrow[sr]) * K_];
#pragma unroll
        for (int w = 0; w < 16; w += 4) {
            float4 qq = ld4(qp + w);
            qreg[w] = qq.x; qreg[w + 1] = qq.y; qreg[w + 2] = qq.z; qreg[w + 3] = qq.w;
        }
    }
    const int prg4 = (t >> 5) * 4, ptc4 = (t & 31) * 4;   // PV mapping
    float acc[4][4] = {{0.f}};
    float accX = 0.f;
    const int xr = (t < 128) ? (t >> 2) : 0, xo = t & 3;
    float lpart = 0.f;
    const int* adjrow = &adj[(size_t)Nrow[sr] * N_];
    for (int ct = 0; ct < 16; ++ct) {
        const int c0 = ct * 64;
        __syncthreads();
        { // stage K tile
            int row = t >> 2, k4 = (t & 3) * 4;
            float4 kk = ld4(&kg[(size_t)(hh * NG + b * N_ + c0 + row) * K_ + k4]);
            st4(&Ks[row][k4], kk);
        }
        for (int idx = t; idx < 64 * 33; idx += 256) { // stage V tile
            int row = idx / 33, c4 = (idx - row * 33) * 4;
            float4 vv = ld4(&vg[(size_t)(hh * NG + b * N_ + c0 + row) * CP + c4]);
            st4(&Vs[row][c4], vv);
        }
        __syncthreads();
        // scores -> P = exp(masked leaky(qk/4)) (no max-sub needed; values O(1))
#pragma unroll
        for (int j = 0; j < 8; ++j) {
            int c = sc0 + 8 * j;
            float4 ka = ld4(&Ks[c][0]), kb4 = ld4(&Ks[c][4]), kc4 = ld4(&Ks[c][8]), kd = ld4(&Ks[c][12]);
            float dot = qreg[0]*ka.x + qreg[1]*ka.y + qreg[2]*ka.z + qreg[3]*ka.w
                      + qreg[4]*kb4.x + qreg[5]*kb4.y + qreg[6]*kb4.z + qreg[7]*kb4.w
                      + qreg[8]*kc4.x + qreg[9]*kc4.y + qreg[10]*kc4.z + qreg[11]*kc4.w
                      + qreg[12]*kd.x + qreg[13]*kd.y + qreg[14]*kd.z + qreg[15]*kd.w;
            float s = dot * 0.25f;
            s = (s >= 0.f) ? s : 0.2f * s;
            float p = adjrow[c0 + c] ? __expf(s) : 0.f;
            lpart += p;
            Pt[c][sr] = p;
        }
        __syncthreads();
        // O += P^T-tile @ V-tile (4x4 register tile per thread)
#pragma unroll 4
        for (int c = 0; c < 64; ++c) {
            float4 pv = ld4(&Pt[c][prg4]);
            float4 vv = ld4(&Vs[c][ptc4]);
            const float* pp = (const float*)&pv;
            const float* vp = (const float*)&vv;
#pragma unroll
            for (int ri = 0; ri < 4; ++ri)
#pragma unroll
                for (int oi = 0; oi < 4; ++oi) acc[ri][oi] += pp[ri] * vp[oi];
            if (t < 128) accX += Pt[c][xr] * Vs[c][128 + xo];
        }
    }
    lpart += __shfl_xor(lpart, 1);
    lpart += __shfl_xor(lpart, 2);
    lpart += __shfl_xor(lpart, 4);
    if (sc0 == 0) Linv[sr] = (lpart > 0.f) ? 1.f / lpart : 0.f;
    __syncthreads();
#pragma unroll
    for (int ri = 0; ri < 4; ++ri) {
        int r = prg4 + ri;
        float li = Linv[r];
        float* op = &hp[(size_t)(m0 + r) * 516 + hh * C_ + ptc4];
        op[0] = acc[ri][0] * li; op[1] = acc[ri][1] * li;
        op[2] = acc[ri][2] * li; op[3] = acc[ri][3] * li;
    }
    if (t < 128 && xo == 0)
        hp[(size_t)(m0 + xr) * 516 + hh * C_ + 128] = accX * Linv[xr];
}

// ---------------- K4: node MLP + skip -> cpost[M][CP] ----------------
__global__ __launch_bounds__(256) void k_mlp(
    const float* __restrict__ hp,
    const float* __restrict__ W1, const float* __restrict__ b1,
    const float* __restrict__ W2, const float* __restrict__ b2,
    const float* __restrict__ x, const float* __restrict__ h,
    const int* __restrict__ nb, const int* __restrict__ nn,
    float* __restrict__ cpost) {
    __shared__ float A[16][128];
    __shared__ float Hd[16][CP];
    const int t = threadIdx.x;
    const int m0 = blockIdx.x * 16;
    int rr[9], oo[9];
#pragma unroll
    for (int j = 0; j < 9; ++j) {
        int idx = t + 256 * j;
        if (idx < 16 * C_) { rr[j] = idx / C_; oo[j] = idx - rr[j] * C_; }
        else { rr[j] = -1; oo[j] = 0; }
    }
    float acc[9];
#pragma unroll
    for (int j = 0; j < 9; ++j) acc[j] = (rr[j] >= 0) ? b1[oo[j]] : 0.f;
    for (int kc = 0; kc < 516; kc += 128) {
        int csz = (kc < 512) ? 128 : 4;
        __syncthreads();
        if (csz == 128) {
#pragma unroll
            for (int s = 0; s < 2; ++s) {
                int idx = t + 256 * s;
                int row = idx >> 5, c4 = (idx & 31) * 4;
                st4(&A[row][c4], ld4(&hp[(size_t)(m0 + row) * 516 + kc + c4]));
            }
        } else if (t < 16) {
            st4(&A[t][0], ld4(&hp[(size_t)(m0 + t) * 516 + 512]));
        }
        __syncthreads();
        for (int c = 0; c < csz; ++c) {
            const float* w1r = &W1[(size_t)(kc + c) * C_];
#pragma unroll
            for (int j = 0; j < 9; ++j)
                if (rr[j] >= 0) acc[j] += A[rr[j]][c] * w1r[oo[j]];
        }
    }
    __syncthreads();
#pragma unroll
    for (int j = 0; j < 9; ++j)
        if (rr[j] >= 0) Hd[rr[j]][oo[j]] = fmaxf(acc[j], 0.f);
    __syncthreads();
    float a2[9];
#pragma unroll
    for (int j = 0; j < 9; ++j) a2[j] = (rr[j] >= 0) ? b2[oo[j]] : 0.f;
    for (int c = 0; c < C_; ++c) {
        const float* w2r = &W2[(size_t)c * C_];
#pragma unroll
        for (int j = 0; j < 9; ++j)
            if (rr[j] >= 0) a2[j] += Hd[rr[j]][c] * w2r[oo[j]];
    }
#pragma unroll
    for (int j = 0; j < 9; ++j) {
        if (rr[j] < 0) continue;
        int m = m0 + rr[j], o = oo[j];
        int b = nb[m], n = nn[m];
        float sk = (o < 65) ? x[(b * N_ + n) * 65 + o] : h[(b * N_ + n) * D_ + (o - 65)];
        cpost[(size_t)m * CP + o] = a2[j] + sk;
    }
}

// ---------------- K5: hypernetwork partials: out_part = sum_{d in split} qv_d (sel . W[d] + b[d]) ----------------
__global__ __launch_bounds__(256) void k_hyper(
    const float* __restrict__ src,   // [M][CP]
    const float* __restrict__ Wa, const float* __restrict__ ba,
    const float* __restrict__ Wb, const float* __restrict__ bb,
    const float* __restrict__ qv,
    float* __restrict__ parts, int two_calls, int dpb) {
    __shared__ float selT[C_][68];
    __shared__ float qvT[QV_][68];
    const int t = threadIdx.x;
    const int m0 = blockIdx.x * 64;
    const int spc = 32 / dpb;
    int call, ds;
    if (two_calls) { call = blockIdx.y / spc; ds = blockIdx.y % spc; }
    else { call = 0; ds = blockIdx.y; }
    const int d0 = ds * dpb;
    const float* W = call ? Wb : Wa;
    const float* bias = call ? bb : ba;
    for (int idx = t; idx < 64 * 33; idx += 256) {
        int r = idx / 33, i4 = (idx - r * 33) * 4;
        float4 v4 = ld4(&src[(size_t)(m0 + r) * CP + i4]);
        const float* vv = (const float*)&v4;
#pragma unroll
        for (int w = 0; w < 4; ++w) { int i = i4 + w; if (i < C_) selT[i][r] = vv[w]; }
    }
    for (int idx = t; idx < 64 * 8; idx += 256) {
        int r = idx >> 3, d4 = (idx & 7) * 4;
        float4 v4 = ld4(&qv[(size_t)(m0 + r) * QV_ + d4]);
        const float* vv = (const float*)&v4;
#pragma unroll
        for (int w = 0; w < 4; ++w) qvT[d4 + w][r] = vv[w];
    }
    __syncthreads();
    const int r0 = (t >> 4) * 4, o0 = (t & 15) * 4;
    float acc[4][4] = {{0.f}};
    for (int dg = 0; dg < dpb; ++dg) {
        int d = d0 + dg;
        float4 b4 = ld4(&bias[(size_t)d * D_ + o0]);
        const float* Wrow = &W[((size_t)d * C_) * D_ + o0];
        float part[4][4] = {{0.f}};
        for (int i = 0; i < C_; ++i) {
            float4 s4 = ld4(&selT[i][r0]);
            float4 w4 = ld4(Wrow + (size_t)i * D_);
            const float* sp = (const float*)&s4;
            const float* wp = (const float*)&w4;
#pragma unroll
            for (int ri = 0; ri < 4; ++ri)
#pragma unroll
                for (int oi = 0; oi < 4; ++oi) part[ri][oi] += sp[ri] * wp[oi];
        }
        float4 q4 = ld4(&qvT[d][r0]);
        const float* qp = (const float*)&q4;
        const float* bp = (const float*)&b4;
#pragma unroll
        for (int ri = 0; ri < 4; ++ri)
#pragma unroll
            for (int oi = 0; oi < 4; ++oi) acc[ri][oi] += qp[ri] * (part[ri][oi] + bp[oi]);
    }
    const int sl = call * spc + ds;
#pragma unroll
    for (int ri = 0; ri < 4; ++ri)
        st4(&parts[((size_t)sl * M_ + m0 + r0 + ri) * D_ + o0],
            make_float4(acc[ri][0], acc[ri][1], acc[ri][2], acc[ri][3]));
}

// ---------------- K5b: build cin[M][CP] = [x_sel, sigmoid(r)*h_sel, 0pad] ----------------
__global__ void k_build_cin(const float* __restrict__ x, const float* __restrict__ h,
                            const int* __restrict__ nb, const int* __restrict__ nn,
                            const float* __restrict__ pru, float* __restrict__ cin) {
    int idx = blockIdx.x * 256 + threadIdx.x;
    if (idx >= M_ * CP) return;
    int m = idx / CP, i = idx - m * CP;
    int b = nb[m], n = nn[m];
    float val;
    if (i < 65) val = x[(b * N_ + n) * 65 + i];
    else if (i < C_) {
        int o = i - 65;
        size_t base = (size_t)m * D_ + o;
        const size_t S = (size_t)M_ * D_;
        float s = pru[base] + pru[S + base] + pru[2 * S + base] + pru[3 * S + base];
        float rv = 1.f / (1.f + __expf(-s));
        val = rv * h[(b * N_ + n) * D_ + o];
    } else val = 0.f;
    cin[idx] = val;
}

// ---------------- K5d: final gate ----------------
__global__ void k_final(const float* __restrict__ pru, const float* __restrict__ pc,
                        const float* __restrict__ cin, float* __restrict__ out) {
    int idx = blockIdx.x * 256 + threadIdx.x;
    if (idx >= M_ * D_) return;
    int m = idx >> 6, o = idx & 63;
    size_t base = (size_t)m * D_ + o;
    const size_t S = (size_t)M_ * D_;
    float su = pru[4 * S + base] + pru[5 * S + base] + pru[6 * S + base] + pru[7 * S + base];
    float uv = 1.f / (1.f + __expf(-su));
    float sc = pc[base] + pc[S + base] + pc[2 * S + base] + pc[3 * S + base]
             + pc[4 * S + base] + pc[5 * S + base] + pc[6 * S + base] + pc[7 * S + base];
    float cand = tanhf(sc);
    float hn = cin[(size_t)m * CP + 65 + o];
    out[idx] = (1.f - uv) * hn + uv * cand;
}

extern "C" void kernel_launch(void* const* d_in, const int* in_sizes, int n_in,
                              void* d_out, int out_size, void* d_ws, size_t ws_size,
                              hipStream_t stream) {
    const float* x   = (const float*)d_in[0];
    const float* h   = (const float*)d_in[1];
    const float* qv  = (const float*)d_in[2];
    const int*   adj = (const int*)d_in[3];
    const int*   nb  = (const int*)d_in[4];
    const int*   nn  = (const int*)d_in[5];
    const float* Wq  = (const float*)d_in[6];
    const float* bq  = (const float*)d_in[7];
    const float* Wk  = (const float*)d_in[8];
    const float* bk  = (const float*)d_in[9];
    const float* Wv  = (const float*)d_in[10];
    const float* bv  = (const float*)d_in[11];
    const float* W1  = (const float*)d_in[12];
    const float* b1  = (const float*)d_in[13];
    const float* W2  = (const float*)d_in[14];
    const float* b2  = (const float*)d_in[15];
    const float* Wr  = (const float*)d_in[16];
    const float* br  = (const float*)d_in[17];
    const float* Wu  = (const float*)d_in[18];
    const float* bu  = (const float*)d_in[19];
    const float* Wc  = (const float*)d_in[20];
    const float* bc  = (const float*)d_in[21];
    float* ws = (float*)d_ws;
    float* out = (float*)d_out;

    float* Wvp   = ws + o_Wvp;
    float* qo    = ws + o_q;
    float* ko    = ws + o_k;
    float* vo    = ws + o_v;
    float* hp    = ws + o_hp;
    float* cpost = ws + o_cpost;
    float* pru   = ws + o_pru;
    float* cin   = ws + o_cin;
    float* pc    = ws + o_pc;

    k_prep<<<(H_ * C_ * CP + 255) / 256, 256, 0, stream>>>(Wv, Wvp);
    k_qkv<<<dim3(NG / 64, H_), 256, 0, stream>>>(x, h, Wq, bq, Wk, bk, Wvp, bv, qo, ko, vo);
    k_attn<<<dim3(M_ / 32, H_), 256, 0, stream>>>(qo, ko, vo, adj, nb, nn, hp);
    k_mlp<<<M_ / 16, 256, 0, stream>>>(hp, W1, b1, W2, b2, x, h, nb, nn, cpost);
    k_hyper<<<dim3(M_ / 64, 8), 256, 0, stream>>>(cpost, Wr, br, Wu, bu, qv, pru, 1, 8);
    k_build_cin<<<(M_ * CP) / 256, 256, 0, stream>>>(x, h, nb, nn, pru, cin);
    k_hyper<<<dim3(M_ / 64, 8), 256, 0, stream>>>(cin, Wc, bc, Wc, bc, qv, pc, 0, 4);
    k_final<<<(M_ * D_) / 256, 256, 0, stream>>>(pru, pc, cin, out);
}

// Round 2
// 647.574 us; speedup vs baseline: 1.5013x; 1.5013x over previous
//
#include <hip/hip_runtime.h>

#define DEVINL __device__ __forceinline__

constexpr int B_ = 8, N_ = 1024, D_ = 64, H_ = 4, QV_ = 32;
constexpr int C_ = 129, K_ = 16, M_ = 4096;
constexpr int CP = 132;              // padded C (multiple of 4)
constexpr int NG = B_ * N_;          // 8192 nodes total

// ---- workspace layout (float offsets) ----
constexpr size_t o_Wvp   = 0;                                   // H*C*CP padded Wv
constexpr size_t o_q     = o_Wvp + (size_t)H_ * C_ * CP;        // H*NG*K
constexpr size_t o_k     = o_q   + (size_t)H_ * NG * K_;        // H*NG*K
constexpr size_t o_v     = o_k   + (size_t)H_ * NG * K_;        // H*NG*CP (padded)
constexpr size_t o_hp    = o_v   + (size_t)H_ * NG * CP;        // M*516 attn_cat
constexpr size_t o_cpost = o_hp  + (size_t)M_ * 516;            // M*CP
constexpr size_t o_W1p   = o_cpost + (size_t)M_ * CP;           // 516*CP
constexpr size_t o_W2p   = o_W1p + (size_t)516 * CP;            // 129*CP
// aliases (lifetimes disjoint)
constexpr size_t o_pru = o_v;      // 8*M*64  (after attn, v dead)
constexpr size_t o_cin = o_q;      // M*CP    (after attn, q+k dead)
constexpr size_t o_pc  = o_hp;     // 8*M*64  (after mlp, hp dead)

DEVINL float4 ld4(const float* p) { return *reinterpret_cast<const float4*>(p); }
DEVINL void st4(float* p, float4 v) { *reinterpret_cast<float4*>(p) = v; }

// ---------------- K0: pad Wv,W1,W2 into [*][CP] layouts ----------------
__global__ void k_prep(const float* __restrict__ Wv, float* __restrict__ Wvp,
                       const float* __restrict__ W1, float* __restrict__ W1p,
                       const float* __restrict__ W2, float* __restrict__ W2p) {
    int idx = blockIdx.x * 256 + threadIdx.x;
    const int totV = H_ * C_ * CP;   // 68112
    const int tot1 = 516 * CP;       // 68112
    const int tot2 = C_ * CP;        // 17028
    if (idx < totV) {
        int hh = idx / (C_ * CP); int rem = idx - hh * C_ * CP;
        int cc = rem / CP;        int o  = rem - cc * CP;
        Wvp[idx] = (o < C_) ? Wv[(hh * C_ + cc) * C_ + o] : 0.f;
    } else if (idx < totV + tot1) {
        int r = (idx - totV) / CP, o = (idx - totV) - ((idx - totV) / CP) * CP;
        W1p[r * CP + o] = (o < C_) ? W1[r * C_ + o] : 0.f;
    } else if (idx < totV + tot1 + tot2) {
        int j = idx - totV - tot1;
        int r = j / CP, o = j - r * CP;
        W2p[r * CP + o] = (o < C_) ? W2[r * C_ + o] : 0.f;
    }
}

// ---------------- K1: combined -> q,k (all nodes), v (padded) ----------------
__global__ __launch_bounds__(256) void k_qkv(
    const float* __restrict__ x, const float* __restrict__ h,
    const float* __restrict__ Wq, const float* __restrict__ bq,
    const float* __restrict__ Wk, const float* __restrict__ bk,
    const float* __restrict__ Wvp, const float* __restrict__ bv,
    float* __restrict__ qo, float* __restrict__ ko, float* __restrict__ vo) {
    __shared__ float Cs[64][CP];
    const int t = threadIdx.x;
    const int g0 = blockIdx.x * 64;
    const int hh = blockIdx.y;
    for (int idx = t; idx < 64 * C_; idx += 256) {
        int r = idx / C_, cc = idx - r * C_;
        int g = g0 + r; int b = g >> 10, n = g & (N_ - 1);
        Cs[r][cc] = (cc < 65) ? x[(b * N_ + n) * 65 + cc]
                              : h[(b * N_ + n) * D_ + (cc - 65)];
    }
    __syncthreads();
    // q and k: thread -> row r=t>>2, k-quad kb=(t&3)*4
    {
        const int r = t >> 2, kb = (t & 3) * 4;
        float aq[4], ak[4];
#pragma unroll
        for (int j = 0; j < 4; ++j) { aq[j] = bq[hh * K_ + kb + j]; ak[j] = bk[hh * K_ + kb + j]; }
        for (int cc = 0; cc < C_; ++cc) {
            float s = Cs[r][cc];
            float4 wq = ld4(&Wq[(size_t)(hh * C_ + cc) * K_ + kb]);
            float4 wk = ld4(&Wk[(size_t)(hh * C_ + cc) * K_ + kb]);
            aq[0] += s * wq.x; aq[1] += s * wq.y; aq[2] += s * wq.z; aq[3] += s * wq.w;
            ak[0] += s * wk.x; ak[1] += s * wk.y; ak[2] += s * wk.z; ak[3] += s * wk.w;
        }
        size_t gi = (size_t)(hh * NG + g0 + r) * K_ + kb;
        st4(&qo[gi], make_float4(aq[0], aq[1], aq[2], aq[3]));
        st4(&ko[gi], make_float4(ak[0], ak[1], ak[2], ak[3]));
    }
    // v main cols 0..127 (float4 per thread-output)
    for (int jj = 0; jj < 8; ++jj) {
        int idx = t + 256 * jj;
        int r = idx >> 5, o4 = (idx & 31) * 4;
        float a0 = bv[hh * C_ + o4 + 0], a1 = bv[hh * C_ + o4 + 1],
              a2 = bv[hh * C_ + o4 + 2], a3 = bv[hh * C_ + o4 + 3];
        for (int cc = 0; cc < C_; ++cc) {
            float s = Cs[r][cc];
            float4 w = ld4(&Wvp[(size_t)(hh * C_ + cc) * CP + o4]);
            a0 += s * w.x; a1 += s * w.y; a2 += s * w.z; a3 += s * w.w;
        }
        st4(&vo[(size_t)(hh * NG + g0 + r) * CP + o4], make_float4(a0, a1, a2, a3));
    }
    // v col 128 + zero pads
    if (t < 64) {
        int r = t;
        float a = bv[hh * C_ + 128];
        for (int cc = 0; cc < C_; ++cc) a += Cs[r][cc] * Wvp[(size_t)(hh * C_ + cc) * CP + 128];
        float* vp = &vo[(size_t)(hh * NG + g0 + r) * CP];
        vp[128] = a; vp[129] = 0.f; vp[130] = 0.f; vp[131] = 0.f;
    }
}

// ---------------- K3: fused masked-leaky-softmax attention, selected rows ----------------
__global__ __launch_bounds__(256) void k_attn(
    const float* __restrict__ qg, const float* __restrict__ kg, const float* __restrict__ vg,
    const int* __restrict__ adj, const int* __restrict__ nodes_b, const int* __restrict__ nodes_n,
    float* __restrict__ hp) {
    __shared__ float Ks[64][20];
    __shared__ float Vs[64][CP];
    __shared__ float Pt[64][36];
    __shared__ float Linv[32];
    __shared__ int Nrow[32];
    const int t = threadIdx.x;
    const int m0 = blockIdx.x * 32;
    const int hh = blockIdx.y;
    const int b = nodes_b[m0];
    if (t < 32) Nrow[t] = nodes_n[m0 + t];
    __syncthreads();
    const int sr = t >> 3, sc0 = t & 7;              // score mapping
    float qreg[16];
    {
        const float* qp = &qg[(size_t)(hh * NG + b * N_ + Nrow[sr]) * K_];
#pragma unroll
        for (int w = 0; w < 16; w += 4) {
            float4 qq = ld4(qp + w);
            qreg[w] = qq.x; qreg[w + 1] = qq.y; qreg[w + 2] = qq.z; qreg[w + 3] = qq.w;
        }
    }
    const int prg4 = (t >> 5) * 4, ptc4 = (t & 31) * 4;   // PV mapping
    float acc[4][4] = {{0.f}};
    float accX = 0.f;
    const int xr = (t < 128) ? (t >> 2) : 0, xo = t & 3;
    float lpart = 0.f;
    const int* adjrow = &adj[(size_t)Nrow[sr] * N_];
    for (int ct = 0; ct < 16; ++ct) {
        const int c0 = ct * 64;
        __syncthreads();
        { // stage K tile
            int row = t >> 2, k4 = (t & 3) * 4;
            float4 kk = ld4(&kg[(size_t)(hh * NG + b * N_ + c0 + row) * K_ + k4]);
            st4(&Ks[row][k4], kk);
        }
        for (int idx = t; idx < 64 * 33; idx += 256) { // stage V tile
            int row = idx / 33, c4 = (idx - row * 33) * 4;
            float4 vv = ld4(&vg[(size_t)(hh * NG + b * N_ + c0 + row) * CP + c4]);
            st4(&Vs[row][c4], vv);
        }
        __syncthreads();
        // scores -> P = exp(masked leaky(qk/4)) (no max-sub needed; values O(1))
#pragma unroll
        for (int j = 0; j < 8; ++j) {
            int c = sc0 + 8 * j;
            float4 ka = ld4(&Ks[c][0]), kb4 = ld4(&Ks[c][4]), kc4 = ld4(&Ks[c][8]), kd = ld4(&Ks[c][12]);
            float dot = qreg[0]*ka.x + qreg[1]*ka.y + qreg[2]*ka.z + qreg[3]*ka.w
                      + qreg[4]*kb4.x + qreg[5]*kb4.y + qreg[6]*kb4.z + qreg[7]*kb4.w
                      + qreg[8]*kc4.x + qreg[9]*kc4.y + qreg[10]*kc4.z + qreg[11]*kc4.w
                      + qreg[12]*kd.x + qreg[13]*kd.y + qreg[14]*kd.z + qreg[15]*kd.w;
            float s = dot * 0.25f;
            s = (s >= 0.f) ? s : 0.2f * s;
            float p = adjrow[c0 + c] ? __expf(s) : 0.f;
            lpart += p;
            Pt[c][sr] = p;
        }
        __syncthreads();
        // O += P^T-tile @ V-tile (4x4 register tile per thread)
#pragma unroll 4
        for (int c = 0; c < 64; ++c) {
            float4 pv = ld4(&Pt[c][prg4]);
            float4 vv = ld4(&Vs[c][ptc4]);
            const float* pp = (const float*)&pv;
            const float* vp = (const float*)&vv;
#pragma unroll
            for (int ri = 0; ri < 4; ++ri)
#pragma unroll
                for (int oi = 0; oi < 4; ++oi) acc[ri][oi] += pp[ri] * vp[oi];
            if (t < 128) accX += Pt[c][xr] * Vs[c][128 + xo];
        }
    }
    lpart += __shfl_xor(lpart, 1);
    lpart += __shfl_xor(lpart, 2);
    lpart += __shfl_xor(lpart, 4);
    if (sc0 == 0) Linv[sr] = (lpart > 0.f) ? 1.f / lpart : 0.f;
    __syncthreads();
#pragma unroll
    for (int ri = 0; ri < 4; ++ri) {
        int r = prg4 + ri;
        float li = Linv[r];
        float* op = &hp[(size_t)(m0 + r) * 516 + hh * C_ + ptc4];
        op[0] = acc[ri][0] * li; op[1] = acc[ri][1] * li;
        op[2] = acc[ri][2] * li; op[3] = acc[ri][3] * li;
    }
    if (t < 128 && xo == 0)
        hp[(size_t)(m0 + xr) * 516 + hh * C_ + 128] = accX * Linv[xr];
}

// ---------------- K4: node MLP + skip -> cpost[M][CP] (tiled GEMM rewrite) ----------------
// block = 32 rows; T[CP][36] holds A^T chunk then hidden^T; 4x4 register tiles.
__global__ __launch_bounds__(256) void k_mlp(
    const float* __restrict__ hp,
    const float* __restrict__ W1p, const float* __restrict__ b1,
    const float* __restrict__ W2p, const float* __restrict__ b2,
    const float* __restrict__ x, const float* __restrict__ h,
    const int* __restrict__ nb, const int* __restrict__ nn,
    float* __restrict__ cpost) {
    __shared__ float T[CP][36];
    const int t = threadIdx.x;
    const int m0 = blockIdx.x * 32;
    const int r0 = (t >> 5) * 4;          // 8 row-groups * 4 = 32 rows
    const int o0 = (t & 31) * 4;          // 32 col-groups * 4 = 128 cols
    const int rX = t >> 2;                // t<128: extra cols 128..131
    const int oX = 128 + (t & 3);
    float acc[4][4] = {{0.f}};
    float accX = 0.f;
    // ---- GEMM1: hidden = relu(hp @ W1 + b1), k = 516 in 4 chunks ----
    for (int chunk = 0; chunk < 4; ++chunk) {
        const int kc = chunk * 132;
        const int csz = (chunk < 3) ? 132 : 120;
        __syncthreads();
        for (int idx = t; idx < 32 * 33; idx += 256) {
            int r = idx / 33, i4 = (idx - r * 33) * 4;
            if (i4 + 3 < csz) {
                float4 v4 = ld4(&hp[(size_t)(m0 + r) * 516 + kc + i4]);
                T[i4 + 0][r] = v4.x; T[i4 + 1][r] = v4.y;
                T[i4 + 2][r] = v4.z; T[i4 + 3][r] = v4.w;
            }
        }
        __syncthreads();
        for (int k = 0; k < csz; ++k) {
            float4 a4 = ld4(&T[k][r0]);
            float4 w4 = ld4(&W1p[(size_t)(kc + k) * CP + o0]);
            const float* ap = (const float*)&a4;
            const float* wp = (const float*)&w4;
#pragma unroll
            for (int ri = 0; ri < 4; ++ri)
#pragma unroll
                for (int oi = 0; oi < 4; ++oi) acc[ri][oi] += ap[ri] * wp[oi];
            if (t < 128) accX += T[k][rX] * W1p[(size_t)(kc + k) * CP + oX];
        }
    }
    __syncthreads();
    // write hidden^T (with relu+bias) back into T; pad rows 129..131 = 0
#pragma unroll
    for (int oi = 0; oi < 4; ++oi) {
        int o = o0 + oi;
        float bb = b1[o];
        st4(&T[o][r0], make_float4(fmaxf(acc[0][oi] + bb, 0.f), fmaxf(acc[1][oi] + bb, 0.f),
                                   fmaxf(acc[2][oi] + bb, 0.f), fmaxf(acc[3][oi] + bb, 0.f)));
    }
    if (t < 128) T[oX][rX] = (oX == 128) ? fmaxf(accX + b1[128], 0.f) : 0.f;
    __syncthreads();
    // ---- GEMM2: out = hidden @ W2 + b2 + skip ----
    float acc2[4][4] = {{0.f}};
    float accX2 = 0.f;
    for (int k = 0; k < C_; ++k) {
        float4 a4 = ld4(&T[k][r0]);
        float4 w4 = ld4(&W2p[(size_t)k * CP + o0]);
        const float* ap = (const float*)&a4;
        const float* wp = (const float*)&w4;
#pragma unroll
        for (int ri = 0; ri < 4; ++ri)
#pragma unroll
            for (int oi = 0; oi < 4; ++oi) acc2[ri][oi] += ap[ri] * wp[oi];
        if (t < 128) accX2 += T[k][rX] * W2p[(size_t)k * CP + oX];
    }
#pragma unroll
    for (int ri = 0; ri < 4; ++ri) {
        int m = m0 + r0 + ri;
        int b = nb[m], n = nn[m];
        const float* xr = &x[(b * N_ + n) * 65];
        const float* hr = &h[(b * N_ + n) * D_];
        float o4[4];
#pragma unroll
        for (int oi = 0; oi < 4; ++oi) {
            int o = o0 + oi;
            float sk = (o < 65) ? xr[o] : hr[o - 65];
            o4[oi] = acc2[ri][oi] + b2[o] + sk;
        }
        st4(&cpost[(size_t)m * CP + o0], make_float4(o4[0], o4[1], o4[2], o4[3]));
    }
    if (t < 128) {
        int m = m0 + rX;
        if (oX == 128) {
            int b = nb[m], n = nn[m];
            cpost[(size_t)m * CP + 128] = accX2 + b2[128] + h[(b * N_ + n) * D_ + 63];
        } else {
            cpost[(size_t)m * CP + oX] = 0.f;
        }
    }
}

// ---------------- K5: hypernetwork partials ----------------
__global__ __launch_bounds__(256) void k_hyper(
    const float* __restrict__ src,   // [M][CP]
    const float* __restrict__ Wa, const float* __restrict__ ba,
    const float* __restrict__ Wb, const float* __restrict__ bb,
    const float* __restrict__ qv,
    float* __restrict__ parts, int two_calls, int dpb) {
    __shared__ float selT[C_][68];
    __shared__ float qvT[QV_][68];
    const int t = threadIdx.x;
    const int m0 = blockIdx.x * 64;
    const int spc = 32 / dpb;
    int call, ds;
    if (two_calls) { call = blockIdx.y / spc; ds = blockIdx.y % spc; }
    else { call = 0; ds = blockIdx.y; }
    const int d0 = ds * dpb;
    const float* W = call ? Wb : Wa;
    const float* bias = call ? bb : ba;
    for (int idx = t; idx < 64 * 33; idx += 256) {
        int r = idx / 33, i4 = (idx - r * 33) * 4;
        float4 v4 = ld4(&src[(size_t)(m0 + r) * CP + i4]);
        const float* vv = (const float*)&v4;
#pragma unroll
        for (int w = 0; w < 4; ++w) { int i = i4 + w; if (i < C_) selT[i][r] = vv[w]; }
    }
    for (int idx = t; idx < 64 * 8; idx += 256) {
        int r = idx >> 3, d4 = (idx & 7) * 4;
        float4 v4 = ld4(&qv[(size_t)(m0 + r) * QV_ + d4]);
        const float* vv = (const float*)&v4;
#pragma unroll
        for (int w = 0; w < 4; ++w) qvT[d4 + w][r] = vv[w];
    }
    __syncthreads();
    const int r0 = (t >> 4) * 4, o0 = (t & 15) * 4;
    float acc[4][4] = {{0.f}};
    for (int dg = 0; dg < dpb; ++dg) {
        int d = d0 + dg;
        float4 b4 = ld4(&bias[(size_t)d * D_ + o0]);
        const float* Wrow = &W[((size_t)d * C_) * D_ + o0];
        float part[4][4] = {{0.f}};
        for (int i = 0; i < C_; ++i) {
            float4 s4 = ld4(&selT[i][r0]);
            float4 w4 = ld4(Wrow + (size_t)i * D_);
            const float* sp = (const float*)&s4;
            const float* wp = (const float*)&w4;
#pragma unroll
            for (int ri = 0; ri < 4; ++ri)
#pragma unroll
                for (int oi = 0; oi < 4; ++oi) part[ri][oi] += sp[ri] * wp[oi];
        }
        float4 q4 = ld4(&qvT[d][r0]);
        const float* qp = (const float*)&q4;
        const float* bp = (const float*)&b4;
#pragma unroll
        for (int ri = 0; ri < 4; ++ri)
#pragma unroll
            for (int oi = 0; oi < 4; ++oi) acc[ri][oi] += qp[ri] * (part[ri][oi] + bp[oi]);
    }
    const int sl = call * spc + ds;
#pragma unroll
    for (int ri = 0; ri < 4; ++ri)
        st4(&parts[((size_t)sl * M_ + m0 + r0 + ri) * D_ + o0],
            make_float4(acc[ri][0], acc[ri][1], acc[ri][2], acc[ri][3]));
}

// ---------------- K5b: build cin[M][CP] = [x_sel, sigmoid(r)*h_sel, 0pad] ----------------
__global__ void k_build_cin(const float* __restrict__ x, const float* __restrict__ h,
                            const int* __restrict__ nb, const int* __restrict__ nn,
                            const float* __restrict__ pru, float* __restrict__ cin) {
    int idx = blockIdx.x * 256 + threadIdx.x;
    if (idx >= M_ * CP) return;
    int m = idx / CP, i = idx - m * CP;
    int b = nb[m], n = nn[m];
    float val;
    if (i < 65) val = x[(b * N_ + n) * 65 + i];
    else if (i < C_) {
        int o = i - 65;
        size_t base = (size_t)m * D_ + o;
        const size_t S = (size_t)M_ * D_;
        float s = pru[base] + pru[S + base] + pru[2 * S + base] + pru[3 * S + base];
        float rv = 1.f / (1.f + __expf(-s));
        val = rv * h[(b * N_ + n) * D_ + o];
    } else val = 0.f;
    cin[idx] = val;
}

// ---------------- K5d: final gate ----------------
__global__ void k_final(const float* __restrict__ pru, const float* __restrict__ pc,
                        const float* __restrict__ cin, float* __restrict__ out) {
    int idx = blockIdx.x * 256 + threadIdx.x;
    if (idx >= M_ * D_) return;
    int m = idx >> 6, o = idx & 63;
    size_t base = (size_t)m * D_ + o;
    const size_t S = (size_t)M_ * D_;
    float su = pru[4 * S + base] + pru[5 * S + base] + pru[6 * S + base] + pru[7 * S + base];
    float uv = 1.f / (1.f + __expf(-su));
    float sc = pc[base] + pc[S + base] + pc[2 * S + base] + pc[3 * S + base]
             + pc[4 * S + base] + pc[5 * S + base] + pc[6 * S + base] + pc[7 * S + base];
    float cand = tanhf(sc);
    float hn = cin[(size_t)m * CP + 65 + o];
    out[idx] = (1.f - uv) * hn + uv * cand;
}

extern "C" void kernel_launch(void* const* d_in, const int* in_sizes, int n_in,
                              void* d_out, int out_size, void* d_ws, size_t ws_size,
                              hipStream_t stream) {
    const float* x   = (const float*)d_in[0];
    const float* h   = (const float*)d_in[1];
    const float* qv  = (const float*)d_in[2];
    const int*   adj = (const int*)d_in[3];
    const int*   nb  = (const int*)d_in[4];
    const int*   nn  = (const int*)d_in[5];
    const float* Wq  = (const float*)d_in[6];
    const float* bq  = (const float*)d_in[7];
    const float* Wk  = (const float*)d_in[8];
    const float* bk  = (const float*)d_in[9];
    const float* Wv  = (const float*)d_in[10];
    const float* bv  = (const float*)d_in[11];
    const float* W1  = (const float*)d_in[12];
    const float* b1  = (const float*)d_in[13];
    const float* W2  = (const float*)d_in[14];
    const float* b2  = (const float*)d_in[15];
    const float* Wr  = (const float*)d_in[16];
    const float* br  = (const float*)d_in[17];
    const float* Wu  = (const float*)d_in[18];
    const float* bu  = (const float*)d_in[19];
    const float* Wc  = (const float*)d_in[20];
    const float* bc  = (const float*)d_in[21];
    float* ws = (float*)d_ws;
    float* out = (float*)d_out;

    float* Wvp   = ws + o_Wvp;
    float* qo    = ws + o_q;
    float* ko    = ws + o_k;
    float* vo    = ws + o_v;
    float* hp    = ws + o_hp;
    float* cpost = ws + o_cpost;
    float* W1p   = ws + o_W1p;
    float* W2p   = ws + o_W2p;
    float* pru   = ws + o_pru;
    float* cin   = ws + o_cin;
    float* pc    = ws + o_pc;

    const int prep_tot = H_ * C_ * CP + 516 * CP + C_ * CP;
    k_prep<<<(prep_tot + 255) / 256, 256, 0, stream>>>(Wv, Wvp, W1, W1p, W2, W2p);
    k_qkv<<<dim3(NG / 64, H_), 256, 0, stream>>>(x, h, Wq, bq, Wk, bk, Wvp, bv, qo, ko, vo);
    k_attn<<<dim3(M_ / 32, H_), 256, 0, stream>>>(qo, ko, vo, adj, nb, nn, hp);
    k_mlp<<<M_ / 32, 256, 0, stream>>>(hp, W1p, b1, W2p, b2, x, h, nb, nn, cpost);
    k_hyper<<<dim3(M_ / 64, 8), 256, 0, stream>>>(cpost, Wr, br, Wu, bu, qv, pru, 1, 8);
    k_build_cin<<<(M_ * CP) / 256, 256, 0, stream>>>(x, h, nb, nn, pru, cin);
    k_hyper<<<dim3(M_ / 64, 8), 256, 0, stream>>>(cin, Wc, bc, Wc, bc, qv, pc, 0, 4);
    k_final<<<(M_ * D_) / 256, 256, 0, stream>>>(pru, pc, cin, out);
}